// Round 13
// baseline (372.434 us; speedup 1.0000x reference)
//
#include <hip/hip_runtime.h>

// Round 19: BK as a template param. FFN2/ATTN_RES are GRID-limited to 2
// blocks/CU (512 blocks) — occupancy 19% is not a resource cap. At BNT=64 a
// wave issues only 16 MFMA per barrier pair vs a multi-hundred-cycle
// vmcnt-drain. BKT=128 for these two: K-steps halve, 32 MFMA/barrier-pair,
// LDS 48KB still fits 3 blocks (grid stays the binder; m132's occupancy trap
// does not apply). GELU/QKV keep BKT=64 (their grids want 3-4 blocks/CU).
// BKT=64 path is algebraically identical to R18's code. Rest unchanged.

typedef __bf16 bf16;
typedef __bf16 bf16x8 __attribute__((ext_vector_type(8)));
typedef float f32x4 __attribute__((ext_vector_type(4)));

#define NROWS 4096   // B*S
#define DM 1024
#define SEQ 2048
#define NHEAD 16
#define DKH 64
#define DFF 4096
#define QSCALE 0.18033688f   // 0.125 * log2(e), folded into Q at QKV epilogue

#define GLL16(gptr, lptr) \
  __builtin_amdgcn_global_load_lds((const __attribute__((address_space(1))) void*)(gptr), \
                                   (__attribute__((address_space(3))) void*)(lptr), 16, 0, 0)

// ---------------- private scratch (allocated at dlopen, NOT inside kernel_launch) ----
static char* g_scratch = nullptr;
namespace {
struct ScratchInit {
  ScratchInit() {
    void* p = nullptr;
    if (hipMalloc(&p, (size_t)128 * 1024 * 1024) == hipSuccess) g_scratch = (char*)p;
  }
};
static ScratchInit g_scratch_init;
}

__device__ inline unsigned cvt_pk_bf16(float lo, float hi) {
  unsigned r;
  asm("v_cvt_pk_bf16_f32 %0, %1, %2" : "=v"(r) : "v"(lo), "v"(hi));
  return r;
}

// ---------------- LayerNorm (fp32 in, bf16 out) ----------------
__global__ __launch_bounds__(256) void ln_kernel(const float* __restrict__ inp,
                                                 const float* __restrict__ gamma,
                                                 const float* __restrict__ beta,
                                                 bf16* __restrict__ out) {
  int row = blockIdx.x;
  int t = threadIdx.x;
  float4 xv = *((const float4*)(inp + (size_t)row * DM) + t);
  float v[4] = {xv.x, xv.y, xv.z, xv.w};
  float s = 0.f, sq = 0.f;
#pragma unroll
  for (int i = 0; i < 4; i++) { s += v[i]; sq += v[i] * v[i]; }
#pragma unroll
  for (int m = 32; m >= 1; m >>= 1) { s += __shfl_xor(s, m); sq += __shfl_xor(sq, m); }
  __shared__ float rs[4], rq[4];
  int w = t >> 6, lane = t & 63;
  if (lane == 0) { rs[w] = s; rq[w] = sq; }
  __syncthreads();
  s = rs[0] + rs[1] + rs[2] + rs[3];
  sq = rq[0] + rq[1] + rq[2] + rq[3];
  float mu = s * (1.f / DM);
  float var = sq * (1.f / DM) - mu * mu;
  float rinv = rsqrtf(var + 1e-5f);
  float4 gv = *((const float4*)gamma + t);
  float4 bv = *((const float4*)beta + t);
  float g[4] = {gv.x, gv.y, gv.z, gv.w}, b[4] = {bv.x, bv.y, bv.z, bv.w};
  bf16 ov[4];
#pragma unroll
  for (int i = 0; i < 4; i++) ov[i] = (bf16)((v[i] - mu) * rinv * g[i] + b[i]);
  *(uint2*)(out + (size_t)row * DM + t * 4) = *(uint2*)ov;
}

// ---------------- bias concat (bq|bk|bv -> 3072 floats) ----------------
__global__ __launch_bounds__(256) void concat_bias(const float* __restrict__ bq,
                                                   const float* __restrict__ bk,
                                                   const float* __restrict__ bv,
                                                   float* __restrict__ cat) {
  int i = blockIdx.x * 256 + threadIdx.x;
  float v = (i < 1024) ? bq[i] : (i < 2048 ? bk[i - 1024] : bv[i - 2048]);
  cat[i] = v;
}

// ---------------- Transpose fp32 [R][C] -> bf16 [C][R] ----------------
__global__ __launch_bounds__(1024) void transpose_f32_bf16(const float* __restrict__ in,
                                                           bf16* __restrict__ out,
                                                           int R, int C) {
  __shared__ bf16 tile[32][33];
  int x = blockIdx.x * 32 + threadIdx.x;
  int y = blockIdx.y * 32 + threadIdx.y;
  tile[threadIdx.y][threadIdx.x] = (bf16)in[(size_t)y * C + x];
  __syncthreads();
  int ox = blockIdx.y * 32 + threadIdx.x;
  int oy = blockIdx.x * 32 + threadIdx.y;
  out[(size_t)oy * R + ox] = tile[threadIdx.x][threadIdx.y];
}

// ---------------- Batched 1024x1024 fp32 -> bf16 transpose (Wq,Wk,Wv,Wo) ------
__global__ __launch_bounds__(1024) void transpose4_f32_bf16(
    const float* __restrict__ i0, const float* __restrict__ i1,
    const float* __restrict__ i2, const float* __restrict__ i3,
    bf16* __restrict__ o0, bf16* __restrict__ o1,
    bf16* __restrict__ o2, bf16* __restrict__ o3) {
  __shared__ bf16 tile[32][33];
  int z = blockIdx.z;
  const float* in = (z == 0) ? i0 : (z == 1) ? i1 : (z == 2) ? i2 : i3;
  bf16* out = (z == 0) ? o0 : (z == 1) ? o1 : (z == 2) ? o2 : o3;
  int x = blockIdx.x * 32 + threadIdx.x;
  int y = blockIdx.y * 32 + threadIdx.y;
  tile[threadIdx.y][threadIdx.x] = (bf16)in[(size_t)y * 1024 + x];
  __syncthreads();
  int ox = blockIdx.y * 32 + threadIdx.x;
  int oy = blockIdx.x * 32 + threadIdx.y;
  out[(size_t)oy * 1024 + ox] = tile[threadIdx.x][threadIdx.y];
}

// ---------------- Transpose bf16 [R][C] -> [C][R] with k-slot permutation ------
// For attention's PV B-operand under swapped-QK: actual k = 16a+4q+r (within a
// 32-k block; a=(k>>4)&1, q=(k>>2)&3, r=k&3) stored at position q*8+a*4+r, so a
// contiguous bf16x8 load at quad*8 yields P's k-slot order. Verified in R11/R15.
__global__ __launch_bounds__(1024) void transpose_bf16_vperm(const bf16* __restrict__ in,
                                                             bf16* __restrict__ out,
                                                             int R, int C) {
  __shared__ bf16 tile[32][33];
  size_t zoff = (size_t)blockIdx.z * (size_t)R * (size_t)C;
  int x = blockIdx.x * 32 + threadIdx.x;
  int y = blockIdx.y * 32 + threadIdx.y;
  tile[threadIdx.y][threadIdx.x] = in[zoff + (size_t)y * C + x];
  __syncthreads();
  int ox = blockIdx.y * 32 + threadIdx.x;   // k index
  int oy = blockIdx.x * 32 + threadIdx.y;   // d index
  int oxp = (ox & ~31) | (((ox >> 2) & 3) << 3) | (((ox >> 4) & 1) << 2) | (ox & 3);
  out[zoff + (size_t)oy * R + oxp] = tile[threadIdx.x][threadIdx.y];
}

// ---------------- GEMM: C[M][N] = A[M][K] * Bt[N][K]^T + bias, fused epilogues ----------
// XOR-swizzled LDS: 16B chunk c of row r lives at slot c^(r&MSK), MSK=BKT/8-1.
// SWZ=1: XCD-chunked grid remap (2x4 super-grid) — FFN2 only (R13/R14 data).
// BKT=128 for grid-limited BNT=64 GEMMs (halves barrier count; LDS 48KB still
// fits >=2 blocks so the grid remains the occupancy binder).
#define BM 128

#define EPI_QKV3 0      // fused QKV: bf16 scatter to [B,H,S,DKH] x3, Q scaled by QSCALE
#define EPI_ATTN_RES 1  // outf fp32 = acc + bias + add (x fp32)
#define EPI_GELU 2      // outb bf16 = gelu(acc + bias)
#define EPI_FFN2 3      // outf fp32 = acc + bias + add (res fp32)

// BNT = 128: waves 2x2 (64x64 each), acc[4][4]. BNT = 64: waves 4x1 (32x64), acc[2][4].
template<int EPI, int BNT, int SWZ, int BKT>
__global__ __launch_bounds__(256, 2) void gemm_bt(
    const bf16* __restrict__ A, const bf16* __restrict__ Bt,
    const float* __restrict__ bias, int Kd, int N,
    bf16* __restrict__ outb, float* __restrict__ outf,
    const float* __restrict__ add) {
  constexpr int MS = (BNT == 128) ? 4 : 2;
  constexpr int CH = BKT / 8;       // 16B chunks per row
  constexpr int RW = 64 / CH;       // rows staged per wave per GLL16 call
  constexpr int MSK = CH - 1;
  constexpr int KKN = BKT / 32;     // MFMA sub-K count
  __shared__ bf16 As[BM * BKT];
  __shared__ bf16 Bs[BNT * BKT];
  int t = threadIdx.x;
  int bx, by;
  if (SWZ) {
    int NXT = gridDim.x, NYT = gridDim.y;
    int L = blockIdx.x + NXT * blockIdx.y;
    int xcd = L & 7, i = L >> 3;
    int RX = NXT >> 1, RY = NYT >> 2;
    bx = (xcd & 1) * RX + (i % RX);
    by = (xcd >> 1) * RY + (i / RX);
  } else {
    bx = blockIdx.x; by = blockIdx.y;
  }
  int m0 = by * BM, n0 = bx * BNT;
  int w = t >> 6, lane = t & 63, ln = lane & 15, quad = lane >> 4;
  int wm = (BNT == 128) ? (w >> 1) * 64 : w * 32;
  int wn = (BNT == 128) ? (w & 1) * 64 : 0;
  f32x4 acc[MS][4];
#pragma unroll
  for (int i2 = 0; i2 < MS; i2++)
#pragma unroll
    for (int j = 0; j < 4; j++) acc[i2][j] = (f32x4){0.f, 0.f, 0.f, 0.f};

  int lr = lane / CH, lc = lane % CH;
  int gcol = (lc ^ ((w * RW + lr) & MSK)) * 8;  // j-invariant (call stride ≡ 0 mod CH rows)
  const bf16* Ab = A + (size_t)(m0 + w * RW + lr) * Kd + gcol;
  const bf16* Bb = Bt + (size_t)(n0 + w * RW + lr) * Kd + gcol;
  bf16* AsW = As + (w * RW) * BKT;  // wave-uniform base; HW appends lane*16B
  bf16* BsW = Bs + (w * RW) * BKT;

  for (int k0 = 0; k0 < Kd; k0 += BKT) {
    __syncthreads();  // previous iteration's fragment reads complete
#pragma unroll
    for (int j = 0; j < BM / (4 * RW); j++)
      GLL16(Ab + (size_t)(4 * RW * j) * Kd + k0, AsW + 4 * RW * j * BKT);
#pragma unroll
    for (int j = 0; j < BNT / (4 * RW); j++)
      GLL16(Bb + (size_t)(4 * RW * j) * Kd + k0, BsW + 4 * RW * j * BKT);
    __syncthreads();  // drains vmcnt -> staged data visible
#pragma unroll
    for (int kk = 0; kk < KKN; kk++) {
      bf16x8 af[MS], bfr[4];
#pragma unroll
      for (int ms = 0; ms < MS; ms++) {
        int r = wm + ms * 16 + ln;
        af[ms] = *(const bf16x8*)(As + r * BKT + (((kk * 4 + quad) ^ (r & MSK)) * 8));
      }
#pragma unroll
      for (int ns = 0; ns < 4; ns++) {
        int r = wn + ns * 16 + ln;
        bfr[ns] = *(const bf16x8*)(Bs + r * BKT + (((kk * 4 + quad) ^ (r & MSK)) * 8));
      }
#pragma unroll
      for (int ms = 0; ms < MS; ms++)
#pragma unroll
        for (int ns = 0; ns < 4; ns++)
          acc[ms][ns] = __builtin_amdgcn_mfma_f32_16x16x32_bf16(af[ms], bfr[ns], acc[ms][ns], 0, 0, 0);
    }
  }

#pragma unroll
  for (int ms = 0; ms < MS; ms++) {
#pragma unroll
    for (int ns = 0; ns < 4; ns++) {
      int col = n0 + wn + ns * 16 + ln;
      float bv = bias[col];
#pragma unroll
      for (int r = 0; r < 4; r++) {
        int row = m0 + wm + ms * 16 + quad * 4 + r;
        float val = acc[ms][ns][r] + bv;
        if (EPI == EPI_QKV3) {
          int which = col >> 10, cc = col & 1023;
          int h = cc >> 6, dk = cc & 63;
          float sc = (which == 0) ? QSCALE : 1.f;
          int b = row >> 11, sx = row & 2047;
          outb[(size_t)which * (4 << 20) +
               ((((size_t)b * NHEAD + h) * SEQ) + sx) * DKH + dk] = (bf16)(val * sc);
        } else if (EPI == EPI_ATTN_RES) {
          size_t idx = (size_t)row * DM + col;
          outf[idx] = val + add[idx];
        } else if (EPI == EPI_GELU) {
          float gl = 0.5f * val * (1.f + erff(val * 0.7071067811865475f));
          outb[(size_t)row * N + col] = (bf16)gl;
        } else {
          size_t idx = (size_t)row * DM + col;
          outf[idx] = val + add[idx];
        }
      }
    }
  }
}

// ---------------- Flash attention: paired q-tiles, swapped-QK in-register P ----
// Q (pre-scaled), K: [BH][S][64]; Vp: [BH][64][S] (k-slot permuted); out: bf16.
// Grid 1024: bh = lin&31 (XCD L2 locality), jp = 31-(lin>>5) (pair-LPT).
// Block owns q-rows [64jp,64jp+64) as two 32-row tiles; both have ktmax=jp so
// each 16KB K/V load feeds 72 MFMA. s = mfma(K,Q): lane ln = q, (quad,r) = k.
// P packed to bf16 A-frags via v_cvt_pk_bf16_f32 — zero LDS in the loop.
#define OSTR 68   // fp32 combine row stride (2-way conflicts only)

__global__ __launch_bounds__(256) void attn_kernel(
    const bf16* __restrict__ Q, const bf16* __restrict__ K,
    const bf16* __restrict__ Vt, bf16* __restrict__ out) {
  __shared__ float smem[2 * 64 * OSTR + 256];  // 35.8KB: Ob[2][64][OSTR] + Lb[4][64]
  int lin = blockIdx.x;
  int bh = lin & 31;
  int jp = 31 - (lin >> 5);            // pair index, LPT: heaviest first
  int t = threadIdx.x, w = t >> 6, lane = t & 63, ln = lane & 15, quad = lane >> 4;
  int qbase = jp * 64;
  size_t bhS = (size_t)bh * SEQ;
  const bf16* Vg0 = Vt + (size_t)bh * DKH * SEQ;

  bf16x8 qa[2][2][2];
#pragma unroll
  for (int u = 0; u < 2; u++)
#pragma unroll
    for (int m = 0; m < 2; m++)
#pragma unroll
      for (int ks = 0; ks < 2; ks++)
        qa[u][m][ks] = *(const bf16x8*)(Q + (bhS + qbase + u * 32 + m * 16 + ln) * DKH + ks * 32 + quad * 8);

  bf16x8 ones;
#pragma unroll
  for (int i = 0; i < 8; i++) ones[i] = (bf16)1.0f;

  f32x4 o[2][2][4];
#pragma unroll
  for (int u = 0; u < 2; u++)
#pragma unroll
    for (int m = 0; m < 2; m++)
#pragma unroll
      for (int i = 0; i < 4; i++) o[u][m][i] = (f32x4){0.f, 0.f, 0.f, 0.f};
  f32x4 accl[2][2];
#pragma unroll
  for (int u = 0; u < 2; u++)
#pragma unroll
    for (int m = 0; m < 2; m++) accl[u][m] = (f32x4){0.f, 0.f, 0.f, 0.f};

  int ktmax = jp;
  for (int kt = w; kt <= ktmax; kt += 4) {
    const bf16* Kg = K + (bhS + kt * 64) * DKH;
    bf16x8 kbf[8], vbf[8];
#pragma unroll
    for (int ns = 0; ns < 4; ns++)
#pragma unroll
      for (int ks = 0; ks < 2; ks++)
        kbf[ns * 2 + ks] = *(const bf16x8*)(Kg + (ns * 16 + ln) * DKH + ks * 32 + quad * 8);
#pragma unroll
    for (int ns = 0; ns < 4; ns++)
#pragma unroll
      for (int ks = 0; ks < 2; ks++)
        vbf[ns * 2 + ks] = *(const bf16x8*)(Vg0 + (size_t)(ns * 16 + ln) * SEQ + kt * 64 + ks * 32 + quad * 8);

    bf16x8 pa[2][2][2];
#pragma unroll
    for (int u = 0; u < 2; u++) {
      f32x4 s[2][4];
#pragma unroll
      for (int m = 0; m < 2; m++)
#pragma unroll
        for (int ns = 0; ns < 4; ns++) s[m][ns] = (f32x4){0.f, 0.f, 0.f, 0.f};
#pragma unroll
      for (int ns = 0; ns < 4; ns++)
#pragma unroll
        for (int m = 0; m < 2; m++) {
          s[m][ns] = __builtin_amdgcn_mfma_f32_16x16x32_bf16(kbf[ns * 2], qa[u][m][0], s[m][ns], 0, 0, 0);
          s[m][ns] = __builtin_amdgcn_mfma_f32_16x16x32_bf16(kbf[ns * 2 + 1], qa[u][m][1], s[m][ns], 0, 0, 0);
        }
      if (kt == ktmax) {
#pragma unroll
        for (int m = 0; m < 2; m++)
#pragma unroll
          for (int ns = 0; ns < 4; ns++)
#pragma unroll
            for (int r = 0; r < 4; r++) {
              int qrow = qbase + u * 32 + m * 16 + ln;
              int kpos = kt * 64 + ns * 16 + quad * 4 + r;
              if (kpos > qrow) s[m][ns][r] = -30000.f;
            }
      }
#pragma unroll
      for (int m = 0; m < 2; m++)
#pragma unroll
        for (int ns = 0; ns < 4; ns++)
#pragma unroll
          for (int r = 0; r < 4; r++)
            s[m][ns][r] = __builtin_amdgcn_exp2f(s[m][ns][r]);
#pragma unroll
      for (int m = 0; m < 2; m++)
#pragma unroll
        for (int j = 0; j < 2; j++) {
          union { bf16x8 v; unsigned uu[4]; } pk;
          pk.uu[0] = cvt_pk_bf16(s[m][2 * j][0], s[m][2 * j][1]);
          pk.uu[1] = cvt_pk_bf16(s[m][2 * j][2], s[m][2 * j][3]);
          pk.uu[2] = cvt_pk_bf16(s[m][2 * j + 1][0], s[m][2 * j + 1][1]);
          pk.uu[3] = cvt_pk_bf16(s[m][2 * j + 1][2], s[m][2 * j + 1][3]);
          pa[u][m][j] = pk.v;
        }
    }
#pragma unroll
    for (int u = 0; u < 2; u++)
#pragma unroll
      for (int m = 0; m < 2; m++) {
        accl[u][m] = __builtin_amdgcn_mfma_f32_16x16x32_bf16(pa[u][m][0], ones, accl[u][m], 0, 0, 0);
        accl[u][m] = __builtin_amdgcn_mfma_f32_16x16x32_bf16(pa[u][m][1], ones, accl[u][m], 0, 0, 0);
      }
#pragma unroll
    for (int ns2 = 0; ns2 < 4; ns2++)
#pragma unroll
      for (int u = 0; u < 2; u++)
#pragma unroll
        for (int m = 0; m < 2; m++) {
          o[u][m][ns2] = __builtin_amdgcn_mfma_f32_16x16x32_bf16(pa[u][m][0], vbf[ns2 * 2], o[u][m][ns2], 0, 0, 0);
          o[u][m][ns2] = __builtin_amdgcn_mfma_f32_16x16x32_bf16(pa[u][m][1], vbf[ns2 * 2 + 1], o[u][m][ns2], 0, 0, 0);
        }
  }

  // ---- 2-pass combine over 64 rows (LDS used only here) ----
  constexpr int SLAB = 64 * OSTR;
  float* Ob = smem;                  // [2][64][OSTR] fp32
  float* Lb = smem + 2 * SLAB;       // [4][64]
#pragma unroll
  for (int u = 0; u < 2; u++)
#pragma unroll
    for (int m = 0; m < 2; m++) {
      if (w < 2) {
#pragma unroll
        for (int ns2 = 0; ns2 < 4; ns2++)
#pragma unroll
          for (int r = 0; r < 4; r++)
            Ob[w * SLAB + (u * 32 + m * 16 + quad * 4 + r) * OSTR + ns2 * 16 + ln] = o[u][m][ns2][r];
      }
      if (ln == 0) {
#pragma unroll
        for (int r = 0; r < 4; r++) Lb[w * 64 + u * 32 + m * 16 + quad * 4 + r] = accl[u][m][r];
      }
    }
  __syncthreads();
  if (w >= 2) {
#pragma unroll
    for (int u = 0; u < 2; u++)
#pragma unroll
      for (int m = 0; m < 2; m++)
#pragma unroll
        for (int ns2 = 0; ns2 < 4; ns2++)
#pragma unroll
          for (int r = 0; r < 4; r++) {
            int idx = (w - 2) * SLAB + (u * 32 + m * 16 + quad * 4 + r) * OSTR + ns2 * 16 + ln;
            Ob[idx] += o[u][m][ns2][r];
          }
  }
  __syncthreads();

  int r32 = t >> 3, c0 = (t & 7) * 8;
  int b = bh >> 4, h = bh & 15;
#pragma unroll
  for (int u = 0; u < 2; u++) {
    int row = u * 32 + r32;
    float l = Lb[row] + Lb[64 + row] + Lb[128 + row] + Lb[192 + row];
    float inv = 1.f / l;
    bf16 ov[8];
#pragma unroll
    for (int j = 0; j < 8; j++) {
      float v = Ob[row * OSTR + c0 + j] + Ob[SLAB + row * OSTR + c0 + j];
      ov[j] = (bf16)(v * inv);
    }
    *(uint4*)(out + ((size_t)b * SEQ + qbase + row) * DM + h * DKH + c0) = *(uint4*)ov;
  }
}

// ---------------- Launch ----------------
extern "C" void kernel_launch(void* const* d_in, const int* in_sizes, int n_in,
                              void* d_out, int out_size, void* d_ws, size_t ws_size,
                              hipStream_t stream) {
  const float* x    = (const float*)d_in[0];
  // d_in[1] = mask (ignored; causal)
  const float* ln1g = (const float*)d_in[2];
  const float* ln1b = (const float*)d_in[3];
  const float* ln2g = (const float*)d_in[4];
  const float* ln2b = (const float*)d_in[5];
  const float* Wq = (const float*)d_in[6];   const float* bq = (const float*)d_in[7];
  const float* Wk = (const float*)d_in[8];   const float* bk = (const float*)d_in[9];
  const float* Wv = (const float*)d_in[10];  const float* bv = (const float*)d_in[11];
  const float* Wo = (const float*)d_in[12];  const float* bo = (const float*)d_in[13];
  const float* W1 = (const float*)d_in[14];  const float* b1 = (const float*)d_in[15];
  const float* W2 = (const float*)d_in[16];  const float* b2 = (const float*)d_in[17];
  float* outp = (float*)d_out;

  char* scratch = g_scratch ? g_scratch : (char*)d_ws;

  bf16* Wqt = (bf16*)scratch;                    // [3072][1024] contiguous = fused Bt
  bf16* Wkt = Wqt + (1 << 20);
  bf16* Wvt = Wkt + (1 << 20);
  bf16* Wot = Wvt + (1 << 20);
  bf16* W1t = Wot + (1 << 20);                   // 4M elems
  bf16* W2t = W1t + (4 << 20);                   // 4M elems
  bf16* normed = W2t + (4 << 20);                // 4M elems
  bf16* Qb = normed + (4 << 20);                 // Q,K,V contiguous (4M each)
  bf16* Kb = Qb + (4 << 20);
  bf16* Vb = Kb + (4 << 20);
  bf16* Vtb = Vb + (4 << 20);
  bf16* attn_o = Vtb + (4 << 20);                // 4M elems
  float* resf = (float*)(attn_o + (4 << 20));    // 4M floats
  float* bias_cat = resf + (4 << 20);            // 3072 floats
  bf16* h1 = Qb;                                 // alias: Q/K/V/Vt dead after attention

  dim3 b256(256), b1k(32, 32);

  ln_kernel<<<NROWS, b256, 0, stream>>>(x, ln1g, ln1b, normed);
  concat_bias<<<12, b256, 0, stream>>>(bq, bk, bv, bias_cat);

  // Wq,Wk,Wv,Wo in one z=4 batched launch (saves 3 launches)
  transpose4_f32_bf16<<<dim3(32, 32, 4), b1k, 0, stream>>>(
      Wq, Wk, Wv, Wo, Wqt, Wkt, Wvt, Wot);
  transpose_f32_bf16<<<dim3(128, 32), b1k, 0, stream>>>(W1, W1t, 1024, 4096);
  transpose_f32_bf16<<<dim3(32, 128), b1k, 0, stream>>>(W2, W2t, 4096, 1024);

  // fused QKV: N=3072, Bt = Wqt|Wkt|Wvt rows, 24x32 = 768 blocks (3/CU)
  gemm_bt<EPI_QKV3, 128, 0, 64><<<dim3(24, 32), b256, 0, stream>>>(
      normed, Wqt, bias_cat, 1024, 3072, Qb, nullptr, nullptr);

  transpose_bf16_vperm<<<dim3(2, 64, 32), b1k, 0, stream>>>(Vb, Vtb, 2048, 64);

  attn_kernel<<<dim3(1024), b256, 0, stream>>>(Qb, Kb, Vtb, attn_o);

  gemm_bt<EPI_ATTN_RES, 64, 0, 128><<<dim3(16, 32), b256, 0, stream>>>(
      attn_o, Wot, bo, 1024, 1024, nullptr, resf, x);

  ln_kernel<<<NROWS, b256, 0, stream>>>(resf, ln2g, ln2b, normed);

  gemm_bt<EPI_GELU, 128, 0, 64><<<dim3(32, 32), b256, 0, stream>>>(
      normed, W1t, b1, 1024, 4096, h1, nullptr, nullptr);

  gemm_bt<EPI_FFN2, 64, 1, 128><<<dim3(16, 32), b256, 0, stream>>>(
      h1, W2t, b2, 4096, 1024, nullptr, outp, resf);
}

// Round 15
// 355.138 us; speedup vs baseline: 1.0487x; 1.0487x over previous
//
#include <hip/hip_runtime.h>

// Round 21: disambiguate R20's failure. R20 bundled (a) per-u PV fusion (exact
// reassociation, re-audited identical) with (b) __launch_bounds__(256,4) forcing
// VGPR 140->128 (spill-forcing pin — the likely miscompile/corruption source).
// This round: R19's exact passing config + ONLY (a), standard launch_bounds(256).
// If VGPR lands <=128 naturally -> 4 blocks/CU single-round (grid is exactly
// 4/CU of uniform work). If not, neutral and the restructure is validated.
// GEMMs unchanged from R19 (BKT=128 on ATTN_RES/FFN2, SWZ on FFN2).

typedef __bf16 bf16;
typedef __bf16 bf16x8 __attribute__((ext_vector_type(8)));
typedef float f32x4 __attribute__((ext_vector_type(4)));

#define NROWS 4096   // B*S
#define DM 1024
#define SEQ 2048
#define NHEAD 16
#define DKH 64
#define DFF 4096
#define QSCALE 0.18033688f   // 0.125 * log2(e), folded into Q at QKV epilogue

#define GLL16(gptr, lptr) \
  __builtin_amdgcn_global_load_lds((const __attribute__((address_space(1))) void*)(gptr), \
                                   (__attribute__((address_space(3))) void*)(lptr), 16, 0, 0)

// ---------------- private scratch (allocated at dlopen, NOT inside kernel_launch) ----
static char* g_scratch = nullptr;
namespace {
struct ScratchInit {
  ScratchInit() {
    void* p = nullptr;
    if (hipMalloc(&p, (size_t)128 * 1024 * 1024) == hipSuccess) g_scratch = (char*)p;
  }
};
static ScratchInit g_scratch_init;
}

__device__ inline unsigned cvt_pk_bf16(float lo, float hi) {
  unsigned r;
  asm("v_cvt_pk_bf16_f32 %0, %1, %2" : "=v"(r) : "v"(lo), "v"(hi));
  return r;
}

// ---------------- LayerNorm (fp32 in, bf16 out) ----------------
__global__ __launch_bounds__(256) void ln_kernel(const float* __restrict__ inp,
                                                 const float* __restrict__ gamma,
                                                 const float* __restrict__ beta,
                                                 bf16* __restrict__ out) {
  int row = blockIdx.x;
  int t = threadIdx.x;
  float4 xv = *((const float4*)(inp + (size_t)row * DM) + t);
  float v[4] = {xv.x, xv.y, xv.z, xv.w};
  float s = 0.f, sq = 0.f;
#pragma unroll
  for (int i = 0; i < 4; i++) { s += v[i]; sq += v[i] * v[i]; }
#pragma unroll
  for (int m = 32; m >= 1; m >>= 1) { s += __shfl_xor(s, m); sq += __shfl_xor(sq, m); }
  __shared__ float rs[4], rq[4];
  int w = t >> 6, lane = t & 63;
  if (lane == 0) { rs[w] = s; rq[w] = sq; }
  __syncthreads();
  s = rs[0] + rs[1] + rs[2] + rs[3];
  sq = rq[0] + rq[1] + rq[2] + rq[3];
  float mu = s * (1.f / DM);
  float var = sq * (1.f / DM) - mu * mu;
  float rinv = rsqrtf(var + 1e-5f);
  float4 gv = *((const float4*)gamma + t);
  float4 bv = *((const float4*)beta + t);
  float g[4] = {gv.x, gv.y, gv.z, gv.w}, b[4] = {bv.x, bv.y, bv.z, bv.w};
  bf16 ov[4];
#pragma unroll
  for (int i = 0; i < 4; i++) ov[i] = (bf16)((v[i] - mu) * rinv * g[i] + b[i]);
  *(uint2*)(out + (size_t)row * DM + t * 4) = *(uint2*)ov;
}

// ---------------- bias concat (bq|bk|bv -> 3072 floats) ----------------
__global__ __launch_bounds__(256) void concat_bias(const float* __restrict__ bq,
                                                   const float* __restrict__ bk,
                                                   const float* __restrict__ bv,
                                                   float* __restrict__ cat) {
  int i = blockIdx.x * 256 + threadIdx.x;
  float v = (i < 1024) ? bq[i] : (i < 2048 ? bk[i - 1024] : bv[i - 2048]);
  cat[i] = v;
}

// ---------------- Transpose fp32 [R][C] -> bf16 [C][R] ----------------
__global__ __launch_bounds__(1024) void transpose_f32_bf16(const float* __restrict__ in,
                                                           bf16* __restrict__ out,
                                                           int R, int C) {
  __shared__ bf16 tile[32][33];
  int x = blockIdx.x * 32 + threadIdx.x;
  int y = blockIdx.y * 32 + threadIdx.y;
  tile[threadIdx.y][threadIdx.x] = (bf16)in[(size_t)y * C + x];
  __syncthreads();
  int ox = blockIdx.y * 32 + threadIdx.x;
  int oy = blockIdx.x * 32 + threadIdx.y;
  out[(size_t)oy * R + ox] = tile[threadIdx.x][threadIdx.y];
}

// ---------------- Batched 1024x1024 fp32 -> bf16 transpose (Wq,Wk,Wv,Wo) ------
__global__ __launch_bounds__(1024) void transpose4_f32_bf16(
    const float* __restrict__ i0, const float* __restrict__ i1,
    const float* __restrict__ i2, const float* __restrict__ i3,
    bf16* __restrict__ o0, bf16* __restrict__ o1,
    bf16* __restrict__ o2, bf16* __restrict__ o3) {
  __shared__ bf16 tile[32][33];
  int z = blockIdx.z;
  const float* in = (z == 0) ? i0 : (z == 1) ? i1 : (z == 2) ? i2 : i3;
  bf16* out = (z == 0) ? o0 : (z == 1) ? o1 : (z == 2) ? o2 : o3;
  int x = blockIdx.x * 32 + threadIdx.x;
  int y = blockIdx.y * 32 + threadIdx.y;
  tile[threadIdx.y][threadIdx.x] = (bf16)in[(size_t)y * 1024 + x];
  __syncthreads();
  int ox = blockIdx.y * 32 + threadIdx.x;
  int oy = blockIdx.x * 32 + threadIdx.y;
  out[(size_t)oy * 1024 + ox] = tile[threadIdx.x][threadIdx.y];
}

// ---------------- Transpose bf16 [R][C] -> [C][R] with k-slot permutation ------
// For attention's PV B-operand under swapped-QK: actual k = 16a+4q+r (within a
// 32-k block; a=(k>>4)&1, q=(k>>2)&3, r=k&3) stored at position q*8+a*4+r, so a
// contiguous bf16x8 load at quad*8 yields P's k-slot order. Verified in R11/R15.
__global__ __launch_bounds__(1024) void transpose_bf16_vperm(const bf16* __restrict__ in,
                                                             bf16* __restrict__ out,
                                                             int R, int C) {
  __shared__ bf16 tile[32][33];
  size_t zoff = (size_t)blockIdx.z * (size_t)R * (size_t)C;
  int x = blockIdx.x * 32 + threadIdx.x;
  int y = blockIdx.y * 32 + threadIdx.y;
  tile[threadIdx.y][threadIdx.x] = in[zoff + (size_t)y * C + x];
  __syncthreads();
  int ox = blockIdx.y * 32 + threadIdx.x;   // k index
  int oy = blockIdx.x * 32 + threadIdx.y;   // d index
  int oxp = (ox & ~31) | (((ox >> 2) & 3) << 3) | (((ox >> 4) & 1) << 2) | (ox & 3);
  out[zoff + (size_t)oy * R + oxp] = tile[threadIdx.x][threadIdx.y];
}

// ---------------- GEMM: C[M][N] = A[M][K] * Bt[N][K]^T + bias, fused epilogues ----------
// XOR-swizzled LDS: 16B chunk c of row r lives at slot c^(r&MSK), MSK=BKT/8-1.
// SWZ=1: XCD-chunked grid remap (2x4 super-grid) — FFN2 only (R13/R14 data).
// BKT=128 for grid-limited BNT=64 GEMMs (halves barrier count).
#define BM 128

#define EPI_QKV3 0      // fused QKV: bf16 scatter to [B,H,S,DKH] x3, Q scaled by QSCALE
#define EPI_ATTN_RES 1  // outf fp32 = acc + bias + add (x fp32)
#define EPI_GELU 2      // outb bf16 = gelu(acc + bias)
#define EPI_FFN2 3      // outf fp32 = acc + bias + add (res fp32)

// BNT = 128: waves 2x2 (64x64 each), acc[4][4]. BNT = 64: waves 4x1 (32x64), acc[2][4].
template<int EPI, int BNT, int SWZ, int BKT>
__global__ __launch_bounds__(256, 2) void gemm_bt(
    const bf16* __restrict__ A, const bf16* __restrict__ Bt,
    const float* __restrict__ bias, int Kd, int N,
    bf16* __restrict__ outb, float* __restrict__ outf,
    const float* __restrict__ add) {
  constexpr int MS = (BNT == 128) ? 4 : 2;
  constexpr int CH = BKT / 8;       // 16B chunks per row
  constexpr int RW = 64 / CH;       // rows staged per wave per GLL16 call
  constexpr int MSK = CH - 1;
  constexpr int KKN = BKT / 32;     // MFMA sub-K count
  __shared__ bf16 As[BM * BKT];
  __shared__ bf16 Bs[BNT * BKT];
  int t = threadIdx.x;
  int bx, by;
  if (SWZ) {
    int NXT = gridDim.x, NYT = gridDim.y;
    int L = blockIdx.x + NXT * blockIdx.y;
    int xcd = L & 7, i = L >> 3;
    int RX = NXT >> 1, RY = NYT >> 2;
    bx = (xcd & 1) * RX + (i % RX);
    by = (xcd >> 1) * RY + (i / RX);
  } else {
    bx = blockIdx.x; by = blockIdx.y;
  }
  int m0 = by * BM, n0 = bx * BNT;
  int w = t >> 6, lane = t & 63, ln = lane & 15, quad = lane >> 4;
  int wm = (BNT == 128) ? (w >> 1) * 64 : w * 32;
  int wn = (BNT == 128) ? (w & 1) * 64 : 0;
  f32x4 acc[MS][4];
#pragma unroll
  for (int i2 = 0; i2 < MS; i2++)
#pragma unroll
    for (int j = 0; j < 4; j++) acc[i2][j] = (f32x4){0.f, 0.f, 0.f, 0.f};

  int lr = lane / CH, lc = lane % CH;
  int gcol = (lc ^ ((w * RW + lr) & MSK)) * 8;  // j-invariant (call stride ≡ 0 mod CH rows)
  const bf16* Ab = A + (size_t)(m0 + w * RW + lr) * Kd + gcol;
  const bf16* Bb = Bt + (size_t)(n0 + w * RW + lr) * Kd + gcol;
  bf16* AsW = As + (w * RW) * BKT;  // wave-uniform base; HW appends lane*16B
  bf16* BsW = Bs + (w * RW) * BKT;

  for (int k0 = 0; k0 < Kd; k0 += BKT) {
    __syncthreads();  // previous iteration's fragment reads complete
#pragma unroll
    for (int j = 0; j < BM / (4 * RW); j++)
      GLL16(Ab + (size_t)(4 * RW * j) * Kd + k0, AsW + 4 * RW * j * BKT);
#pragma unroll
    for (int j = 0; j < BNT / (4 * RW); j++)
      GLL16(Bb + (size_t)(4 * RW * j) * Kd + k0, BsW + 4 * RW * j * BKT);
    __syncthreads();  // drains vmcnt -> staged data visible
#pragma unroll
    for (int kk = 0; kk < KKN; kk++) {
      bf16x8 af[MS], bfr[4];
#pragma unroll
      for (int ms = 0; ms < MS; ms++) {
        int r = wm + ms * 16 + ln;
        af[ms] = *(const bf16x8*)(As + r * BKT + (((kk * 4 + quad) ^ (r & MSK)) * 8));
      }
#pragma unroll
      for (int ns = 0; ns < 4; ns++) {
        int r = wn + ns * 16 + ln;
        bfr[ns] = *(const bf16x8*)(Bs + r * BKT + (((kk * 4 + quad) ^ (r & MSK)) * 8));
      }
#pragma unroll
      for (int ms = 0; ms < MS; ms++)
#pragma unroll
        for (int ns = 0; ns < 4; ns++)
          acc[ms][ns] = __builtin_amdgcn_mfma_f32_16x16x32_bf16(af[ms], bfr[ns], acc[ms][ns], 0, 0, 0);
    }
  }

#pragma unroll
  for (int ms = 0; ms < MS; ms++) {
#pragma unroll
    for (int ns = 0; ns < 4; ns++) {
      int col = n0 + wn + ns * 16 + ln;
      float bv = bias[col];
#pragma unroll
      for (int r = 0; r < 4; r++) {
        int row = m0 + wm + ms * 16 + quad * 4 + r;
        float val = acc[ms][ns][r] + bv;
        if (EPI == EPI_QKV3) {
          int which = col >> 10, cc = col & 1023;
          int h = cc >> 6, dk = cc & 63;
          float sc = (which == 0) ? QSCALE : 1.f;
          int b = row >> 11, sx = row & 2047;
          outb[(size_t)which * (4 << 20) +
               ((((size_t)b * NHEAD + h) * SEQ) + sx) * DKH + dk] = (bf16)(val * sc);
        } else if (EPI == EPI_ATTN_RES) {
          size_t idx = (size_t)row * DM + col;
          outf[idx] = val + add[idx];
        } else if (EPI == EPI_GELU) {
          float gl = 0.5f * val * (1.f + erff(val * 0.7071067811865475f));
          outb[(size_t)row * N + col] = (bf16)gl;
        } else {
          size_t idx = (size_t)row * DM + col;
          outf[idx] = val + add[idx];
        }
      }
    }
  }
}

// ---------------- Flash attention: paired q-tiles, swapped-QK in-register P ----
// Q (pre-scaled), K: [BH][S][64]; Vp: [BH][64][S] (k-slot permuted); out: bf16.
// Grid 1024: bh = lin&31 (XCD L2 locality), jp = 31-(lin>>5) (pair-LPT).
// Block owns q-rows [64jp,64jp+64) as two 32-row tiles; both have ktmax=jp so
// each 16KB K/V load feeds 72 MFMA. s = mfma(K,Q): lane ln = q, (quad,r) = k.
// P packed to bf16 A-frags via v_cvt_pk_bf16_f32 — zero LDS in the loop.
// PV fused per-u: only pa_l[2][2] (16 VGPR) live, not pa[2][2][2] (32) —
// exact reassociation; NO launch_bounds pin (R20's pin corrupted results).
#define OSTR 68   // fp32 combine row stride (2-way conflicts only)

__global__ __launch_bounds__(256) void attn_kernel(
    const bf16* __restrict__ Q, const bf16* __restrict__ K,
    const bf16* __restrict__ Vt, bf16* __restrict__ out) {
  __shared__ float smem[2 * 64 * OSTR + 256];  // 35.8KB: Ob[2][64][OSTR] + Lb[4][64]
  int lin = blockIdx.x;
  int bh = lin & 31;
  int jp = 31 - (lin >> 5);            // pair index, LPT: heaviest first
  int t = threadIdx.x, w = t >> 6, lane = t & 63, ln = lane & 15, quad = lane >> 4;
  int qbase = jp * 64;
  size_t bhS = (size_t)bh * SEQ;
  const bf16* Vg0 = Vt + (size_t)bh * DKH * SEQ;

  bf16x8 qa[2][2][2];
#pragma unroll
  for (int u = 0; u < 2; u++)
#pragma unroll
    for (int m = 0; m < 2; m++)
#pragma unroll
      for (int ks = 0; ks < 2; ks++)
        qa[u][m][ks] = *(const bf16x8*)(Q + (bhS + qbase + u * 32 + m * 16 + ln) * DKH + ks * 32 + quad * 8);

  bf16x8 ones;
#pragma unroll
  for (int i = 0; i < 8; i++) ones[i] = (bf16)1.0f;

  f32x4 o[2][2][4];
#pragma unroll
  for (int u = 0; u < 2; u++)
#pragma unroll
    for (int m = 0; m < 2; m++)
#pragma unroll
      for (int i = 0; i < 4; i++) o[u][m][i] = (f32x4){0.f, 0.f, 0.f, 0.f};
  f32x4 accl[2][2];
#pragma unroll
  for (int u = 0; u < 2; u++)
#pragma unroll
    for (int m = 0; m < 2; m++) accl[u][m] = (f32x4){0.f, 0.f, 0.f, 0.f};

  int ktmax = jp;
  for (int kt = w; kt <= ktmax; kt += 4) {
    const bf16* Kg = K + (bhS + kt * 64) * DKH;
    bf16x8 kbf[8], vbf[8];
#pragma unroll
    for (int ns = 0; ns < 4; ns++)
#pragma unroll
      for (int ks = 0; ks < 2; ks++)
        kbf[ns * 2 + ks] = *(const bf16x8*)(Kg + (ns * 16 + ln) * DKH + ks * 32 + quad * 8);
#pragma unroll
    for (int ns = 0; ns < 4; ns++)
#pragma unroll
      for (int ks = 0; ks < 2; ks++)
        vbf[ns * 2 + ks] = *(const bf16x8*)(Vg0 + (size_t)(ns * 16 + ln) * SEQ + kt * 64 + ks * 32 + quad * 8);

#pragma unroll
    for (int u = 0; u < 2; u++) {
      // QK^T swapped: lane ln = q-row, (quad,r) within ns-subtile = k
      f32x4 s[2][4];
#pragma unroll
      for (int m = 0; m < 2; m++)
#pragma unroll
        for (int ns = 0; ns < 4; ns++) s[m][ns] = (f32x4){0.f, 0.f, 0.f, 0.f};
#pragma unroll
      for (int ns = 0; ns < 4; ns++)
#pragma unroll
        for (int m = 0; m < 2; m++) {
          s[m][ns] = __builtin_amdgcn_mfma_f32_16x16x32_bf16(kbf[ns * 2], qa[u][m][0], s[m][ns], 0, 0, 0);
          s[m][ns] = __builtin_amdgcn_mfma_f32_16x16x32_bf16(kbf[ns * 2 + 1], qa[u][m][1], s[m][ns], 0, 0, 0);
        }
      if (kt == ktmax) {
#pragma unroll
        for (int m = 0; m < 2; m++)
#pragma unroll
          for (int ns = 0; ns < 4; ns++)
#pragma unroll
            for (int r = 0; r < 4; r++) {
              int qrow = qbase + u * 32 + m * 16 + ln;
              int kpos = kt * 64 + ns * 16 + quad * 4 + r;
              if (kpos > qrow) s[m][ns][r] = -30000.f;
            }
      }
#pragma unroll
      for (int m = 0; m < 2; m++)
#pragma unroll
        for (int ns = 0; ns < 4; ns++)
#pragma unroll
          for (int r = 0; r < 4; r++)
            s[m][ns][r] = __builtin_amdgcn_exp2f(s[m][ns][r]);
      bf16x8 pa_l[2][2];
#pragma unroll
      for (int m = 0; m < 2; m++)
#pragma unroll
        for (int j = 0; j < 2; j++) {
          union { bf16x8 v; unsigned uu[4]; } pk;
          pk.uu[0] = cvt_pk_bf16(s[m][2 * j][0], s[m][2 * j][1]);
          pk.uu[1] = cvt_pk_bf16(s[m][2 * j][2], s[m][2 * j][3]);
          pk.uu[2] = cvt_pk_bf16(s[m][2 * j + 1][0], s[m][2 * j + 1][1]);
          pk.uu[3] = cvt_pk_bf16(s[m][2 * j + 1][2], s[m][2 * j + 1][3]);
          pa_l[m][j] = pk.v;
        }
      // row sums + PV immediately (pa_l live range = this u iteration only)
#pragma unroll
      for (int m = 0; m < 2; m++) {
        accl[u][m] = __builtin_amdgcn_mfma_f32_16x16x32_bf16(pa_l[m][0], ones, accl[u][m], 0, 0, 0);
        accl[u][m] = __builtin_amdgcn_mfma_f32_16x16x32_bf16(pa_l[m][1], ones, accl[u][m], 0, 0, 0);
      }
#pragma unroll
      for (int ns2 = 0; ns2 < 4; ns2++)
#pragma unroll
        for (int m = 0; m < 2; m++) {
          o[u][m][ns2] = __builtin_amdgcn_mfma_f32_16x16x32_bf16(pa_l[m][0], vbf[ns2 * 2], o[u][m][ns2], 0, 0, 0);
          o[u][m][ns2] = __builtin_amdgcn_mfma_f32_16x16x32_bf16(pa_l[m][1], vbf[ns2 * 2 + 1], o[u][m][ns2], 0, 0, 0);
        }
    }
  }

  // ---- 2-pass combine over 64 rows (LDS used only here) ----
  constexpr int SLAB = 64 * OSTR;
  float* Ob = smem;                  // [2][64][OSTR] fp32
  float* Lb = smem + 2 * SLAB;       // [4][64]
#pragma unroll
  for (int u = 0; u < 2; u++)
#pragma unroll
    for (int m = 0; m < 2; m++) {
      if (w < 2) {
#pragma unroll
        for (int ns2 = 0; ns2 < 4; ns2++)
#pragma unroll
          for (int r = 0; r < 4; r++)
            Ob[w * SLAB + (u * 32 + m * 16 + quad * 4 + r) * OSTR + ns2 * 16 + ln] = o[u][m][ns2][r];
      }
      if (ln == 0) {
#pragma unroll
        for (int r = 0; r < 4; r++) Lb[w * 64 + u * 32 + m * 16 + quad * 4 + r] = accl[u][m][r];
      }
    }
  __syncthreads();
  if (w >= 2) {
#pragma unroll
    for (int u = 0; u < 2; u++)
#pragma unroll
      for (int m = 0; m < 2; m++)
#pragma unroll
        for (int ns2 = 0; ns2 < 4; ns2++)
#pragma unroll
          for (int r = 0; r < 4; r++) {
            int idx = (w - 2) * SLAB + (u * 32 + m * 16 + quad * 4 + r) * OSTR + ns2 * 16 + ln;
            Ob[idx] += o[u][m][ns2][r];
          }
  }
  __syncthreads();

  int r32 = t >> 3, c0 = (t & 7) * 8;
  int b = bh >> 4, h = bh & 15;
#pragma unroll
  for (int u = 0; u < 2; u++) {
    int row = u * 32 + r32;
    float l = Lb[row] + Lb[64 + row] + Lb[128 + row] + Lb[192 + row];
    float inv = 1.f / l;
    bf16 ov[8];
#pragma unroll
    for (int j = 0; j < 8; j++) {
      float v = Ob[row * OSTR + c0 + j] + Ob[SLAB + row * OSTR + c0 + j];
      ov[j] = (bf16)(v * inv);
    }
    *(uint4*)(out + ((size_t)b * SEQ + qbase + row) * DM + h * DKH + c0) = *(uint4*)ov;
  }
}

// ---------------- Launch ----------------
extern "C" void kernel_launch(void* const* d_in, const int* in_sizes, int n_in,
                              void* d_out, int out_size, void* d_ws, size_t ws_size,
                              hipStream_t stream) {
  const float* x    = (const float*)d_in[0];
  // d_in[1] = mask (ignored; causal)
  const float* ln1g = (const float*)d_in[2];
  const float* ln1b = (const float*)d_in[3];
  const float* ln2g = (const float*)d_in[4];
  const float* ln2b = (const float*)d_in[5];
  const float* Wq = (const float*)d_in[6];   const float* bq = (const float*)d_in[7];
  const float* Wk = (const float*)d_in[8];   const float* bk = (const float*)d_in[9];
  const float* Wv = (const float*)d_in[10];  const float* bv = (const float*)d_in[11];
  const float* Wo = (const float*)d_in[12];  const float* bo = (const float*)d_in[13];
  const float* W1 = (const float*)d_in[14];  const float* b1 = (const float*)d_in[15];
  const float* W2 = (const float*)d_in[16];  const float* b2 = (const float*)d_in[17];
  float* outp = (float*)d_out;

  char* scratch = g_scratch ? g_scratch : (char*)d_ws;

  bf16* Wqt = (bf16*)scratch;                    // [3072][1024] contiguous = fused Bt
  bf16* Wkt = Wqt + (1 << 20);
  bf16* Wvt = Wkt + (1 << 20);
  bf16* Wot = Wvt + (1 << 20);
  bf16* W1t = Wot + (1 << 20);                   // 4M elems
  bf16* W2t = W1t + (4 << 20);                   // 4M elems
  bf16* normed = W2t + (4 << 20);                // 4M elems
  bf16* Qb = normed + (4 << 20);                 // Q,K,V contiguous (4M each)
  bf16* Kb = Qb + (4 << 20);
  bf16* Vb = Kb + (4 << 20);
  bf16* Vtb = Vb + (4 << 20);
  bf16* attn_o = Vtb + (4 << 20);                // 4M elems
  float* resf = (float*)(attn_o + (4 << 20));    // 4M floats
  float* bias_cat = resf + (4 << 20);            // 3072 floats
  bf16* h1 = Qb;                                 // alias: Q/K/V/Vt dead after attention

  dim3 b256(256), b1k(32, 32);

  ln_kernel<<<NROWS, b256, 0, stream>>>(x, ln1g, ln1b, normed);
  concat_bias<<<12, b256, 0, stream>>>(bq, bk, bv, bias_cat);

  // Wq,Wk,Wv,Wo in one z=4 batched launch (saves 3 launches)
  transpose4_f32_bf16<<<dim3(32, 32, 4), b1k, 0, stream>>>(
      Wq, Wk, Wv, Wo, Wqt, Wkt, Wvt, Wot);
  transpose_f32_bf16<<<dim3(128, 32), b1k, 0, stream>>>(W1, W1t, 1024, 4096);
  transpose_f32_bf16<<<dim3(32, 128), b1k, 0, stream>>>(W2, W2t, 4096, 1024);

  // fused QKV: N=3072, Bt = Wqt|Wkt|Wvt rows, 24x32 = 768 blocks (3/CU)
  gemm_bt<EPI_QKV3, 128, 0, 64><<<dim3(24, 32), b256, 0, stream>>>(
      normed, Wqt, bias_cat, 1024, 3072, Qb, nullptr, nullptr);

  transpose_bf16_vperm<<<dim3(2, 64, 32), b1k, 0, stream>>>(Vb, Vtb, 2048, 64);

  attn_kernel<<<dim3(1024), b256, 0, stream>>>(Qb, Kb, Vtb, attn_o);

  gemm_bt<EPI_ATTN_RES, 64, 0, 128><<<dim3(16, 32), b256, 0, stream>>>(
      attn_o, Wot, bo, 1024, 1024, nullptr, resf, x);

  ln_kernel<<<NROWS, b256, 0, stream>>>(resf, ln2g, ln2b, normed);

  gemm_bt<EPI_GELU, 128, 0, 64><<<dim3(32, 32), b256, 0, stream>>>(
      normed, W1t, b1, 1024, 4096, h1, nullptr, nullptr);

  gemm_bt<EPI_FFN2, 64, 1, 128><<<dim3(16, 32), b256, 0, stream>>>(
      h1, W2t, b2, 4096, 1024, nullptr, outp, resf);
}